// Round 13
// baseline (289.421 us; speedup 1.0000x reference)
//
#include <hip/hip_runtime.h>
#include <hip/hip_fp16.h>

constexpr int N_ = 300;
constexpr int R_ = 48;
constexpr int B_ = 1048576;                    // 2^20
constexpr int NBIN3 = 64;                      // 4x4x4 bins over (c0,c1,c2) row-chunks
constexpr int SUBS = 8;                        // sub-cells (XCD-private counter lines)
constexpr int NCELL = NBIN3 * SUBS;            // 512
constexpr int CAP = 2304;                      // per-cell; mean 2048 (+5.7 sigma)
constexpr int CNT_STRIDE = 32;                 // ints; 128B-padded counter cells
constexpr int OVF_CAP = 16384;
constexpr int BPB = 54;                        // 54*256 = 13824 = 2304*6
constexpr unsigned GB_MAIN = NCELL * BPB;      // 27,648 = 8 * 3456
constexpr unsigned XCHUNK = GB_MAIN / 8;       // 3456
constexpr unsigned OVF_BLOCKS = 64;
constexpr unsigned GRID_GATHER = GB_MAIN + OVF_BLOCKS;

// fused prep+scatter grid: 1800 transpose half-rows + 1 vsum + 4096 scatter
constexpr unsigned PS_TR = 1800;
constexpr unsigned PS_VS = 1800;               // block id for vsum
constexpr unsigned PS_SC0 = 1801;
constexpr unsigned GRID_PS = PS_SC0 + B_ / 256;

// ws layout (bytes); end 30,770,432 << 43,664,512 proven
constexpr size_t OFF_MT   = 0;                 // fp16 texture (3,300,300,48) = 25,920,000
constexpr size_t OFF_VSUM = 25920000;          // 144 floats (+pad)
constexpr size_t OFF_CNT  = 25920640;          // int counts[NCELL][32] = 65,536
constexpr size_t OFF_OCUR = 25986176;          // overflow cursor (+pad)
constexpr size_t OFF_OVF  = 25986304;          // u32 ovf[OVF_CAP] = 65,536
constexpr size_t OFF_REC  = 26051840;          // u32 recs[NCELL][CAP] = 4,718,592

typedef float f32x4 __attribute__((ext_vector_type(4)));
union H8 { float4 f4; __half2 h2[4]; };

struct BW { float w00, w01, w10, w11; int o00, o01, o10, o11; };
__device__ inline BW bilin_ix(float ix, float iy) {
    float ix0f = floorf(ix), iy0f = floorf(iy);
    float wx = ix - ix0f, wy = iy - iy0f;
    int ix0 = (int)ix0f, iy0 = (int)iy0f;
    int ix1 = ix0 + 1, iy1 = iy0 + 1;
    BW r;
    r.w00 = (1.0f - wy) * (1.0f - wx);
    r.w01 = (1.0f - wy) * wx;
    r.w10 = wy * (1.0f - wx);
    r.w11 = wy * wx;
    bool bx0 = (unsigned)ix0 < (unsigned)N_;
    bool bx1 = (unsigned)ix1 < (unsigned)N_;
    bool by0 = (unsigned)iy0 < (unsigned)N_;
    bool by1 = (unsigned)iy1 < (unsigned)N_;
    if (!(bx0 && by0)) r.w00 = 0.0f;
    if (!(bx1 && by0)) r.w01 = 0.0f;
    if (!(bx0 && by1)) r.w10 = 0.0f;
    if (!(bx1 && by1)) r.w11 = 0.0f;
    int cx0 = min(max(ix0, 0), N_ - 1), cx1 = min(max(ix1, 0), N_ - 1);
    int cy0 = min(max(iy0, 0), N_ - 1), cy1 = min(max(iy1, 0), N_ - 1);
    r.o00 = (cy0 * N_ + cx0) * R_;
    r.o01 = (cy0 * N_ + cx1) * R_;
    r.o10 = (cy1 * N_ + cx0) * R_;
    r.o11 = (cy1 * N_ + cx1) * R_;
    return r;
}

__device__ inline void plane_xy(int plane, float c0, float c1, float c2,
                                float& xc, float& yc, float& cc) {
    if (plane == 0)      { xc = c1; yc = c2; cc = c0; }
    else if (plane == 1) { xc = c2; yc = c0; cc = c1; }
    else                 { xc = c0; yc = c1; cc = c2; }
}

// one plane's channels [8j, 8j+8) for sample b — shared by gather & overflow
// paths so both are bit-identical (determinism under atomic reordering).
// R13 A/B: REGULAR cached stores (R12 used nontemporal) — fills hit 6.9TB/s
// with cached stores; NT bypasses L2 write-combining.
__device__ inline void sample8(int plane, int j, int b, float c0, float c1, float c2,
                               const __half* __restrict__ M,
                               const float* __restrict__ vsum,
                               float* __restrict__ out) {
    float xc, yc, cc;
    plane_xy(plane, c0, c1, c2, xc, yc, cc);
    float ix = (xc + 1.0f) * 150.0f - 0.5f;
    float iy = (yc + 1.0f) * 150.0f - 0.5f;
    BW w = bilin_ix(ix, iy);
    const __half* Mi = M + (size_t)plane * N_ * N_ * R_;
    int co = 8 * j;

    H8 u00, u01, u10, u11;
    u00.f4 = *reinterpret_cast<const float4*>(Mi + w.o00 + co);
    u01.f4 = *reinterpret_cast<const float4*>(Mi + w.o01 + co);
    u10.f4 = *reinterpret_cast<const float4*>(Mi + w.o10 + co);
    u11.f4 = *reinterpret_cast<const float4*>(Mi + w.o11 + co);

    float vw = 1.0f - 0.5f * fabsf(cc);
    const float4* vs4 = reinterpret_cast<const float4*>(vsum + plane * R_ + co);
    float4 vv0 = vs4[0];
    float4 vv1 = vs4[1];

    float r[8];
#pragma unroll
    for (int k = 0; k < 4; ++k) {
        float2 a00 = __half22float2(u00.h2[k]);
        float2 a01 = __half22float2(u01.h2[k]);
        float2 a10 = __half22float2(u10.h2[k]);
        float2 a11 = __half22float2(u11.h2[k]);
        r[2 * k]     = fmaf(a00.x, w.w00, fmaf(a01.x, w.w01, fmaf(a10.x, w.w10, a11.x * w.w11)));
        r[2 * k + 1] = fmaf(a00.y, w.w00, fmaf(a01.y, w.w01, fmaf(a10.y, w.w10, a11.y * w.w11)));
    }

    f32x4 s0, s1;
    s0.x = r[0] * (vv0.x * vw); s0.y = r[1] * (vv0.y * vw);
    s0.z = r[2] * (vv0.z * vw); s0.w = r[3] * (vv0.w * vw);
    s1.x = r[4] * (vv1.x * vw); s1.y = r[5] * (vv1.y * vw);
    s1.z = r[6] * (vv1.z * vw); s1.w = r[7] * (vv1.w * vw);

    float* outp = out + (size_t)b * 144 + plane * 48 + co;
    *reinterpret_cast<f32x4*>(outp) = s0;
    *(reinterpret_cast<f32x4*>(outp) + 1) = s1;
}

__device__ inline int row_chunk(float c) {
    float i = (c + 1.0f) * 150.0f - 0.5f;
    int row = (int)floorf(i) + 1;            // [0, 300]
    return (row * 4) / 301;                  // [0, 3]
}

// --- fused prep + scatter. Counters pre-zeroed by hipMemsetAsync node. ---
__global__ __launch_bounds__(256) void k_ps(const float* __restrict__ mat,
                                            const float* __restrict__ vec,
                                            const float* __restrict__ coords,
                                            __half2* __restrict__ mt2,
                                            float* __restrict__ vsum,
                                            int* __restrict__ counts,
                                            unsigned* __restrict__ recs,
                                            int* __restrict__ ocur,
                                            unsigned* __restrict__ ovf) {
    __shared__ float tile[R_][151];
    __shared__ int lcnt[NBIN3];
    __shared__ int lbase[NBIN3];
    unsigned bid = blockIdx.x;
    int tid = threadIdx.x;

    if (bid < PS_TR) {
        // transpose half-row: (3,R,N,N) f32 -> (3,N,N,R) fp16
        int i = bid / 600;
        int rem = bid - i * 600;
        int y = rem >> 1;
        int x0 = (rem & 1) * 150;
        const float* src = mat + ((size_t)i * R_ * N_ + y) * N_ + x0;
        for (int idx = tid; idx < R_ * 150; idx += 256) {
            int r = idx / 150, xl = idx - r * 150;
            tile[r][xl] = src[(size_t)r * N_ * N_ + xl];
        }
        __syncthreads();
        __half2* dst = mt2 + ((size_t)(i * N_ + y) * N_ + x0) * (R_ / 2);
        for (int idx = tid; idx < 150 * (R_ / 2); idx += 256) {
            int xl = idx / (R_ / 2), jj = idx - xl * (R_ / 2);
            dst[xl * (R_ / 2) + jj] = __floats2half2_rn(tile[2 * jj][xl], tile[2 * jj + 1][xl]);
        }
        return;
    }
    if (bid == PS_VS) {
        if (tid < 3 * R_) vsum[tid] = 0.5f * (vec[tid * N_ + 149] + vec[tid * N_ + 150]);
        return;
    }

    // scatter: ONE u32 record per b; 1 LDS atomic/sample, 64 global atomics/block.
    if (tid < NBIN3) lcnt[tid] = 0;
    __syncthreads();
    int b = (int)(bid - PS_SC0) * 256 + tid;
    int sub = (int)(bid & 7);                  // == XCD under round-robin dispatch
    float c0 = coords[3 * b], c1 = coords[3 * b + 1], c2 = coords[3 * b + 2];
    int bin = row_chunk(c0) * 16 + row_chunk(c1) * 4 + row_chunk(c2);
    int lpos = atomicAdd(&lcnt[bin], 1);
    __syncthreads();
    if (tid < NBIN3) {
        int cell = tid * SUBS + sub;
        lbase[tid] = atomicAdd(&counts[cell * CNT_STRIDE], lcnt[tid]);
    }
    __syncthreads();
    int pos = lbase[bin] + lpos;
    int cell = bin * SUBS + sub;
    if (pos < CAP) {
        recs[(size_t)cell * CAP + pos] = (unsigned)b;
    } else {
        int o = atomicAdd(ocur, 1);
        if (o < OVF_CAP) ovf[o] = (unsigned)b;
    }
}

// --- gather (+fused overflow): R12 structure, cached stores. ---
__global__ __launch_bounds__(256) void k_gather(const float* __restrict__ coords,
                                                const int* __restrict__ counts,
                                                const unsigned* __restrict__ recs,
                                                const int* __restrict__ ocur,
                                                const unsigned* __restrict__ ovf,
                                                const __half* __restrict__ M,
                                                const float* __restrict__ vsum,
                                                float* __restrict__ out) {
    unsigned bid = blockIdx.x;
    if (bid >= GB_MAIN) {
        int cnt = min(*ocur, OVF_CAP);
        for (int t = (bid - GB_MAIN) * 256 + threadIdx.x; t < cnt; t += OVF_BLOCKS * 256) {
            int b = (int)ovf[t];
            float c0 = coords[3 * b], c1 = coords[3 * b + 1], c2 = coords[3 * b + 2];
#pragma unroll
            for (int p = 0; p < 3; ++p)
                for (int j = 0; j < 6; ++j)
                    sample8(p, j, b, c0, c1, c2, M, vsum, out);
        }
        return;
    }
    unsigned vbid = (bid & 7) * XCHUNK + (bid >> 3);   // cells chunked per XCD
    unsigned cell = vbid / BPB;
    unsigned lb   = vbid - cell * BPB;
    unsigned g = lb * 256 + threadIdx.x;               // [0, 13824)
    unsigned slot = g / 6;                             // [0, 2304)
    unsigned j = g - slot * 6;
    int cnt = min(counts[cell * CNT_STRIDE], CAP);
    if ((int)slot >= cnt) return;

    int b = (int)recs[(size_t)cell * CAP + slot];
    float c0 = coords[3 * b], c1 = coords[3 * b + 1], c2 = coords[3 * b + 2];
#pragma unroll
    for (int p = 0; p < 3; ++p)
        sample8(p, (int)j, b, c0, c1, c2, M, vsum, out);
}

extern "C" void kernel_launch(void* const* d_in, const int* in_sizes, int n_in,
                              void* d_out, int out_size, void* d_ws, size_t ws_size,
                              hipStream_t stream) {
    const float* coords   = (const float*)d_in[0];
    const float* matrices = (const float*)d_in[1];
    const float* vectors  = (const float*)d_in[2];
    float* out = (float*)d_out;

    __half*   mt     = (__half*)((char*)d_ws + OFF_MT);
    float*    vsum   = (float*)((char*)d_ws + OFF_VSUM);
    int*      counts = (int*)((char*)d_ws + OFF_CNT);
    int*      ocur   = (int*)((char*)d_ws + OFF_OCUR);
    unsigned* ovf    = (unsigned*)((char*)d_ws + OFF_OVF);
    unsigned* recs   = (unsigned*)((char*)d_ws + OFF_REC);

    // zero counters + overflow cursor (stream-ordered before k_ps)
    hipMemsetAsync((char*)d_ws + OFF_CNT, 0, OFF_OVF - OFF_CNT, stream);
    hipLaunchKernelGGL(k_ps, dim3(GRID_PS), dim3(256), 0, stream,
                       matrices, vectors, coords, (__half2*)mt, vsum,
                       counts, recs, ocur, ovf);
    hipLaunchKernelGGL(k_gather, dim3(GRID_GATHER), dim3(256), 0, stream,
                       coords, counts, recs, ocur, ovf, mt, vsum, out);
}

// Round 14
// 219.741 us; speedup vs baseline: 1.3171x; 1.3171x over previous
//
#include <hip/hip_runtime.h>
#include <hip/hip_fp16.h>

constexpr int N_ = 300;
constexpr int R_ = 48;
constexpr int B_ = 1048576;                    // 2^20
constexpr int NBIN3 = 64;                      // 4x4x4 bins over (c0,c1,c2) row-chunks
constexpr int SUBS = 16;                       // sub-cells; sub&7 == XCD (stays private)
constexpr int NCELL = NBIN3 * SUBS;            // 1024
constexpr int CAP = 1280;                      // per-cell; mean 1024 (+8 sigma)
constexpr int CNT_STRIDE = 32;                 // ints; 128B-padded counter cells
constexpr int OVF_CAP = 16384;
constexpr int BPB = 30;                        // 30*256 = 7680 = 1280*6
constexpr unsigned GB_MAIN = NCELL * BPB;      // 30,720 = 8 * 3840
constexpr unsigned XCHUNK = GB_MAIN / 8;       // 3840
constexpr unsigned OVF_BLOCKS = 64;
constexpr unsigned GRID_GATHER = GB_MAIN + OVF_BLOCKS;

// fused prep+scatter grid: 1800 transpose half-rows + 1 vsum + 4096 scatter
constexpr unsigned PS_TR = 1800;
constexpr unsigned PS_VS = 1800;               // block id for vsum
constexpr unsigned PS_SC0 = 1801;
constexpr unsigned GRID_PS = PS_SC0 + B_ / 256;

// ws layout (bytes); end 31,360,256 << 43,664,512 proven
constexpr size_t OFF_MT   = 0;                 // fp16 texture (3,300,300,48) = 25,920,000
constexpr size_t OFF_VSUM = 25920000;          // 144 floats (+pad)
constexpr size_t OFF_CNT  = 25920640;          // int counts[NCELL][32] = 131,072
constexpr size_t OFF_OCUR = 26051712;          // overflow cursor (+pad to 128B)
constexpr size_t OFF_OVF  = 26051840;          // u32 ovf[OVF_CAP] = 65,536
constexpr size_t OFF_REC  = 26117376;          // u32 recs[NCELL][CAP] = 5,242,880

typedef float f32x4 __attribute__((ext_vector_type(4)));
union H8 { float4 f4; __half2 h2[4]; };

struct BW { float w00, w01, w10, w11; int o00, o01, o10, o11; };
__device__ inline BW bilin_ix(float ix, float iy) {
    float ix0f = floorf(ix), iy0f = floorf(iy);
    float wx = ix - ix0f, wy = iy - iy0f;
    int ix0 = (int)ix0f, iy0 = (int)iy0f;
    int ix1 = ix0 + 1, iy1 = iy0 + 1;
    BW r;
    r.w00 = (1.0f - wy) * (1.0f - wx);
    r.w01 = (1.0f - wy) * wx;
    r.w10 = wy * (1.0f - wx);
    r.w11 = wy * wx;
    bool bx0 = (unsigned)ix0 < (unsigned)N_;
    bool bx1 = (unsigned)ix1 < (unsigned)N_;
    bool by0 = (unsigned)iy0 < (unsigned)N_;
    bool by1 = (unsigned)iy1 < (unsigned)N_;
    if (!(bx0 && by0)) r.w00 = 0.0f;
    if (!(bx1 && by0)) r.w01 = 0.0f;
    if (!(bx0 && by1)) r.w10 = 0.0f;
    if (!(bx1 && by1)) r.w11 = 0.0f;
    int cx0 = min(max(ix0, 0), N_ - 1), cx1 = min(max(ix1, 0), N_ - 1);
    int cy0 = min(max(iy0, 0), N_ - 1), cy1 = min(max(iy1, 0), N_ - 1);
    r.o00 = (cy0 * N_ + cx0) * R_;
    r.o01 = (cy0 * N_ + cx1) * R_;
    r.o10 = (cy1 * N_ + cx0) * R_;
    r.o11 = (cy1 * N_ + cx1) * R_;
    return r;
}

__device__ inline void plane_xy(int plane, float c0, float c1, float c2,
                                float& xc, float& yc, float& cc) {
    if (plane == 0)      { xc = c1; yc = c2; cc = c0; }
    else if (plane == 1) { xc = c2; yc = c0; cc = c1; }
    else                 { xc = c0; yc = c1; cc = c2; }
}

// one plane's channels [8j, 8j+8) for sample b — shared by gather & overflow
// paths so both are bit-identical. NT stores (R13 A/B: NT beats cached by 68us
// — the 604MB quasi-random output stream must bypass L2).
__device__ inline void sample8(int plane, int j, int b, float c0, float c1, float c2,
                               const __half* __restrict__ M,
                               const float* __restrict__ vsum,
                               float* __restrict__ out) {
    float xc, yc, cc;
    plane_xy(plane, c0, c1, c2, xc, yc, cc);
    float ix = (xc + 1.0f) * 150.0f - 0.5f;
    float iy = (yc + 1.0f) * 150.0f - 0.5f;
    BW w = bilin_ix(ix, iy);
    const __half* Mi = M + (size_t)plane * N_ * N_ * R_;
    int co = 8 * j;

    H8 u00, u01, u10, u11;
    u00.f4 = *reinterpret_cast<const float4*>(Mi + w.o00 + co);
    u01.f4 = *reinterpret_cast<const float4*>(Mi + w.o01 + co);
    u10.f4 = *reinterpret_cast<const float4*>(Mi + w.o10 + co);
    u11.f4 = *reinterpret_cast<const float4*>(Mi + w.o11 + co);

    float vw = 1.0f - 0.5f * fabsf(cc);
    const float4* vs4 = reinterpret_cast<const float4*>(vsum + plane * R_ + co);
    float4 vv0 = vs4[0];
    float4 vv1 = vs4[1];

    float r[8];
#pragma unroll
    for (int k = 0; k < 4; ++k) {
        float2 a00 = __half22float2(u00.h2[k]);
        float2 a01 = __half22float2(u01.h2[k]);
        float2 a10 = __half22float2(u10.h2[k]);
        float2 a11 = __half22float2(u11.h2[k]);
        r[2 * k]     = fmaf(a00.x, w.w00, fmaf(a01.x, w.w01, fmaf(a10.x, w.w10, a11.x * w.w11)));
        r[2 * k + 1] = fmaf(a00.y, w.w00, fmaf(a01.y, w.w01, fmaf(a10.y, w.w10, a11.y * w.w11)));
    }

    f32x4 s0, s1;
    s0.x = r[0] * (vv0.x * vw); s0.y = r[1] * (vv0.y * vw);
    s0.z = r[2] * (vv0.z * vw); s0.w = r[3] * (vv0.w * vw);
    s1.x = r[4] * (vv1.x * vw); s1.y = r[5] * (vv1.y * vw);
    s1.z = r[6] * (vv1.z * vw); s1.w = r[7] * (vv1.w * vw);

    float* outp = out + (size_t)b * 144 + plane * 48 + co;
    __builtin_nontemporal_store(s0, reinterpret_cast<f32x4*>(outp));
    __builtin_nontemporal_store(s1, reinterpret_cast<f32x4*>(outp) + 1);
}

__device__ inline int row_chunk(float c) {
    float i = (c + 1.0f) * 150.0f - 0.5f;
    int row = (int)floorf(i) + 1;            // [0, 300]
    return (row * 4) / 301;                  // [0, 3]
}

// --- fused prep + scatter. Counters pre-zeroed by hipMemsetAsync node.
// sub = bid & 15: 16 subs, each still XCD-private (sub mod 8 == XCD) —
// halves the per-counter-line atomic chain (512 -> 256 RMWs/line).
__global__ __launch_bounds__(256) void k_ps(const float* __restrict__ mat,
                                            const float* __restrict__ vec,
                                            const float* __restrict__ coords,
                                            __half2* __restrict__ mt2,
                                            float* __restrict__ vsum,
                                            int* __restrict__ counts,
                                            unsigned* __restrict__ recs,
                                            int* __restrict__ ocur,
                                            unsigned* __restrict__ ovf) {
    __shared__ float tile[R_][151];
    __shared__ int lcnt[NBIN3];
    __shared__ int lbase[NBIN3];
    unsigned bid = blockIdx.x;
    int tid = threadIdx.x;

    if (bid < PS_TR) {
        // transpose half-row: (3,R,N,N) f32 -> (3,N,N,R) fp16
        int i = bid / 600;
        int rem = bid - i * 600;
        int y = rem >> 1;
        int x0 = (rem & 1) * 150;
        const float* src = mat + ((size_t)i * R_ * N_ + y) * N_ + x0;
        for (int idx = tid; idx < R_ * 150; idx += 256) {
            int r = idx / 150, xl = idx - r * 150;
            tile[r][xl] = src[(size_t)r * N_ * N_ + xl];
        }
        __syncthreads();
        __half2* dst = mt2 + ((size_t)(i * N_ + y) * N_ + x0) * (R_ / 2);
        for (int idx = tid; idx < 150 * (R_ / 2); idx += 256) {
            int xl = idx / (R_ / 2), jj = idx - xl * (R_ / 2);
            dst[xl * (R_ / 2) + jj] = __floats2half2_rn(tile[2 * jj][xl], tile[2 * jj + 1][xl]);
        }
        return;
    }
    if (bid == PS_VS) {
        if (tid < 3 * R_) vsum[tid] = 0.5f * (vec[tid * N_ + 149] + vec[tid * N_ + 150]);
        return;
    }

    // scatter: ONE u32 record per b; 1 LDS atomic/sample, 64 global atomics/block.
    if (tid < NBIN3) lcnt[tid] = 0;
    __syncthreads();
    int b = (int)(bid - PS_SC0) * 256 + tid;
    int sub = (int)(bid & 15);                 // sub&7 == XCD under round-robin
    float c0 = coords[3 * b], c1 = coords[3 * b + 1], c2 = coords[3 * b + 2];
    int bin = row_chunk(c0) * 16 + row_chunk(c1) * 4 + row_chunk(c2);
    int lpos = atomicAdd(&lcnt[bin], 1);
    __syncthreads();
    if (tid < NBIN3) {
        int cell = tid * SUBS + sub;
        lbase[tid] = atomicAdd(&counts[cell * CNT_STRIDE], lcnt[tid]);
    }
    __syncthreads();
    int pos = lbase[bin] + lpos;
    int cell = bin * SUBS + sub;
    if (pos < CAP) {
        recs[(size_t)cell * CAP + pos] = (unsigned)b;
    } else {
        int o = atomicAdd(ocur, 1);
        if (o < OVF_CAP) ovf[o] = (unsigned)b;
    }
}

// --- gather (+fused overflow): R12 structure, NT stores. Cells chunked per
// XCD: 128 consecutive cells = 8 bins -> ~1.7MB texture slice, L2-hot.
__global__ __launch_bounds__(256) void k_gather(const float* __restrict__ coords,
                                                const int* __restrict__ counts,
                                                const unsigned* __restrict__ recs,
                                                const int* __restrict__ ocur,
                                                const unsigned* __restrict__ ovf,
                                                const __half* __restrict__ M,
                                                const float* __restrict__ vsum,
                                                float* __restrict__ out) {
    unsigned bid = blockIdx.x;
    if (bid >= GB_MAIN) {
        int cnt = min(*ocur, OVF_CAP);
        for (int t = (bid - GB_MAIN) * 256 + threadIdx.x; t < cnt; t += OVF_BLOCKS * 256) {
            int b = (int)ovf[t];
            float c0 = coords[3 * b], c1 = coords[3 * b + 1], c2 = coords[3 * b + 2];
#pragma unroll
            for (int p = 0; p < 3; ++p)
                for (int j = 0; j < 6; ++j)
                    sample8(p, j, b, c0, c1, c2, M, vsum, out);
        }
        return;
    }
    unsigned vbid = (bid & 7) * XCHUNK + (bid >> 3);   // cells chunked per XCD
    unsigned cell = vbid / BPB;
    unsigned lb   = vbid - cell * BPB;
    unsigned g = lb * 256 + threadIdx.x;               // [0, 7680)
    unsigned slot = g / 6;                             // [0, 1280)
    unsigned j = g - slot * 6;
    int cnt = min(counts[cell * CNT_STRIDE], CAP);
    if ((int)slot >= cnt) return;

    int b = (int)recs[(size_t)cell * CAP + slot];
    float c0 = coords[3 * b], c1 = coords[3 * b + 1], c2 = coords[3 * b + 2];
#pragma unroll
    for (int p = 0; p < 3; ++p)
        sample8(p, (int)j, b, c0, c1, c2, M, vsum, out);
}

extern "C" void kernel_launch(void* const* d_in, const int* in_sizes, int n_in,
                              void* d_out, int out_size, void* d_ws, size_t ws_size,
                              hipStream_t stream) {
    const float* coords   = (const float*)d_in[0];
    const float* matrices = (const float*)d_in[1];
    const float* vectors  = (const float*)d_in[2];
    float* out = (float*)d_out;

    __half*   mt     = (__half*)((char*)d_ws + OFF_MT);
    float*    vsum   = (float*)((char*)d_ws + OFF_VSUM);
    int*      counts = (int*)((char*)d_ws + OFF_CNT);
    int*      ocur   = (int*)((char*)d_ws + OFF_OCUR);
    unsigned* ovf    = (unsigned*)((char*)d_ws + OFF_OVF);
    unsigned* recs   = (unsigned*)((char*)d_ws + OFF_REC);

    // zero counters + overflow cursor (stream-ordered before k_ps)
    hipMemsetAsync((char*)d_ws + OFF_CNT, 0, OFF_OVF - OFF_CNT, stream);
    hipLaunchKernelGGL(k_ps, dim3(GRID_PS), dim3(256), 0, stream,
                       matrices, vectors, coords, (__half2*)mt, vsum,
                       counts, recs, ocur, ovf);
    hipLaunchKernelGGL(k_gather, dim3(GRID_GATHER), dim3(256), 0, stream,
                       coords, counts, recs, ocur, ovf, mt, vsum, out);
}